// Round 1
// 222.295 us; speedup vs baseline: 1.0469x; 1.0469x over previous
//
#include <hip/hip_runtime.h>

#define F_IN   128
#define F_OUT  128

typedef __attribute__((ext_vector_type(8))) short short8;
typedef __attribute__((ext_vector_type(4))) float floatx4;

__device__ __forceinline__ float bf16u_to_f_lo(unsigned int u) {
    union { unsigned int i; float f; } c; c.i = u << 16; return c.f;
}
__device__ __forceinline__ float bf16u_to_f_hi(unsigned int u) {
    union { unsigned int i; float f; } c; c.i = u & 0xffff0000u; return c.f;
}
__device__ __forceinline__ unsigned short f_to_bf16(float f) {
    union { float f; unsigned int i; } c; c.f = f;
    unsigned int u = c.i;
    u += 0x7fffu + ((u >> 16) & 1u);   // round-to-nearest-even
    return (unsigned short)(u >> 16);
}
__device__ __forceinline__ unsigned int pack2(unsigned short a, unsigned short b) {
    return (unsigned int)a | ((unsigned int)b << 16);
}

// async 16B global -> LDS (wave-uniform LDS base + lane*16)
__device__ __forceinline__ void gload_lds16(const void* g, void* l) {
    __builtin_amdgcn_global_load_lds(
        (const __attribute__((address_space(1))) unsigned int*)g,
        (__attribute__((address_space(3))) unsigned int*)l, 16, 0, 0);
}

// ---------------------------------------------------------------------------
__global__ void zero_kernel(int* __restrict__ p, long n) {
    long i = (long)blockIdx.x * blockDim.x + threadIdx.x;
    long stride = (long)gridDim.x * blockDim.x;
    for (; i < n; i += stride) p[i] = 0;
}

// ---------------------------------------------------------------------------
// CSR build. edge_index arrives int32: src = ei[0..E), dst = ei[E..2E).
// ---------------------------------------------------------------------------
__global__ void hist_kernel(const int* __restrict__ src, int* __restrict__ cnt, int E) {
    int e = blockIdx.x * blockDim.x + threadIdx.x;
    if (e < E) atomicAdd(&cnt[src[e]], 1);
}

__global__ __launch_bounds__(256) void chunk_sums_kernel(const int* __restrict__ cnt,
                                                         int* __restrict__ partials, int n) {
    __shared__ int s[256];
    int b = blockIdx.x, t = threadIdx.x;
    int base = b * 1024 + t * 4;
    int sum = 0;
#pragma unroll
    for (int j = 0; j < 4; ++j) {
        int i = base + j;
        if (i < n) sum += cnt[i];
    }
    s[t] = sum;
    __syncthreads();
    for (int d = 128; d > 0; d >>= 1) {
        if (t < d) s[t] += s[t + d];
        __syncthreads();
    }
    if (t == 0) partials[b] = s[0];
}

// scan within chunk; chunk base recomputed per-block from partials (nch <= 128)
__global__ __launch_bounds__(256) void scan_chunks_kernel(int* __restrict__ off,
                                                          const int* __restrict__ partials,
                                                          int n, int nch) {
    __shared__ int s[256];
    __shared__ int ps[128];
    int b = blockIdx.x, t = threadIdx.x;
    if (t < 128) ps[t] = (t < nch && t < b) ? partials[t] : 0;
    int base = b * 1024 + t * 4;
    int v[4];
#pragma unroll
    for (int j = 0; j < 4; ++j) {
        int i = base + j;
        v[j] = (i < n) ? off[i] : 0;
    }
    int l1 = v[0], l2 = l1 + v[1], l3 = l2 + v[2], tot = l3 + v[3];
    s[t] = tot;
    __syncthreads();
    // reduce partials[0..b) -> ps[0]
    for (int d = 64; d > 0; d >>= 1) {
        if (t < d) ps[t] += ps[t + d];
        __syncthreads();
    }
    for (int d = 1; d < 256; d <<= 1) {
        int val = s[t];
        int add = (t >= d) ? s[t - d] : 0;
        __syncthreads();
        s[t] = val + add;
        __syncthreads();
    }
    int thr_excl = ((t > 0) ? s[t - 1] : 0) + ps[0];
    if (base + 0 < n) off[base + 0] = thr_excl;
    if (base + 1 < n) off[base + 1] = thr_excl + l1;
    if (base + 2 < n) off[base + 2] = thr_excl + l2;
    if (base + 3 < n) off[base + 3] = thr_excl + l3;
}

__global__ void fill_kernel(const int* __restrict__ ei, int* __restrict__ off,
                            int* __restrict__ dst_sorted, int E) {
    int e = blockIdx.x * blockDim.x + threadIdx.x;
    if (e < E) {
        int s = ei[e];
        int d = ei[E + e];
        int p = atomicAdd(&off[s], 1);
        dst_sorted[p] = d;
    }
}

// ---------------------------------------------------------------------------
// convert x (fp32) -> bf16 packed into out row bytes [256,512).
// Last block (when bfrag != nullptr) instead converts W/B into bf16 MFMA
// fragments, frag-lane-major, so the GEMM can async-copy them straight to LDS.
// ---------------------------------------------------------------------------
__global__ __launch_bounds__(256) void convert_x_kernel(const float* __restrict__ x,
                                                        char* __restrict__ outb,
                                                        const float* __restrict__ W,
                                                        const float* __restrict__ Bm,
                                                        uint4* __restrict__ bfrag, int N) {
    if (bfrag && blockIdx.x == gridDim.x - 1) {
        int t = threadIdx.x;
#pragma unroll
        for (int i = 0; i < 16; ++i) {
            int flat = i * 256 + t;          // 0..4095 = (nt*8+s)*64 + lane
            int lane = flat & 63;
            int idx = flat >> 6;
            int nt = idx >> 3, sfrag = idx & 7;
            int n = nt * 16 + (lane & 15);
            int kbase = sfrag * 32 + (lane >> 4) * 8;  // multiple of 8
            const float* srcp = (kbase < 128) ? (W + n * 128 + kbase)
                                              : (Bm + n * 128 + (kbase - 128));
            float4 v0 = *(const float4*)srcp;
            float4 v1 = *(const float4*)(srcp + 4);
            uint4 pk;
            pk.x = pack2(f_to_bf16(v0.x), f_to_bf16(v0.y));
            pk.y = pack2(f_to_bf16(v0.z), f_to_bf16(v0.w));
            pk.z = pack2(f_to_bf16(v1.x), f_to_bf16(v1.y));
            pk.w = pack2(f_to_bf16(v1.z), f_to_bf16(v1.w));
            bfrag[flat] = pk;
        }
        return;
    }
    long tid = (long)blockIdx.x * blockDim.x + threadIdx.x;
    if (tid >= (long)N * 32) return;
    int row = (int)(tid >> 5);
    int seg = (int)(tid & 31);
    float4 v = *(const float4*)(x + (size_t)row * 128 + seg * 4);
    unsigned short r[4] = {f_to_bf16(v.x), f_to_bf16(v.y), f_to_bf16(v.z), f_to_bf16(v.w)};
    *(ushort4*)(outb + (size_t)row * 512 + 256 + seg * 8) =
        make_ushort4(r[0], r[1], r[2], r[3]);
}

// ---------------------------------------------------------------------------
// Gather-aggregate (bf16 in/out, fp32 accumulate). 16 lanes/node, uint4 per
// lane per edge, unrolled by 4 for memory-level parallelism.
// ---------------------------------------------------------------------------
__global__ __launch_bounds__(256) void gather_bf16_kernel(const int* __restrict__ off,
                                                          const int* __restrict__ dst_sorted,
                                                          char* __restrict__ outb, int N) {
    int node = blockIdx.x * 16 + (threadIdx.x >> 4);
    int lane = threadIdx.x & 15;
    if (node >= N) return;
    int start = (node == 0) ? 0 : off[node - 1];
    int end = off[node];
    float acc[8];
#pragma unroll
    for (int i = 0; i < 8; ++i) acc[i] = 0.0f;

    const char* xb = outb;
    int j = start;
    for (; j + 4 <= end; j += 4) {
        int d0 = dst_sorted[j];
        int d1 = dst_sorted[j + 1];
        int d2 = dst_sorted[j + 2];
        int d3 = dst_sorted[j + 3];
        uint4 a = *(const uint4*)(xb + (size_t)d0 * 512 + 256 + lane * 16);
        uint4 b = *(const uint4*)(xb + (size_t)d1 * 512 + 256 + lane * 16);
        uint4 c = *(const uint4*)(xb + (size_t)d2 * 512 + 256 + lane * 16);
        uint4 d = *(const uint4*)(xb + (size_t)d3 * 512 + 256 + lane * 16);
        acc[0] += bf16u_to_f_lo(a.x); acc[1] += bf16u_to_f_hi(a.x);
        acc[2] += bf16u_to_f_lo(a.y); acc[3] += bf16u_to_f_hi(a.y);
        acc[4] += bf16u_to_f_lo(a.z); acc[5] += bf16u_to_f_hi(a.z);
        acc[6] += bf16u_to_f_lo(a.w); acc[7] += bf16u_to_f_hi(a.w);
        acc[0] += bf16u_to_f_lo(b.x); acc[1] += bf16u_to_f_hi(b.x);
        acc[2] += bf16u_to_f_lo(b.y); acc[3] += bf16u_to_f_hi(b.y);
        acc[4] += bf16u_to_f_lo(b.z); acc[5] += bf16u_to_f_hi(b.z);
        acc[6] += bf16u_to_f_lo(b.w); acc[7] += bf16u_to_f_hi(b.w);
        acc[0] += bf16u_to_f_lo(c.x); acc[1] += bf16u_to_f_hi(c.x);
        acc[2] += bf16u_to_f_lo(c.y); acc[3] += bf16u_to_f_hi(c.y);
        acc[4] += bf16u_to_f_lo(c.z); acc[5] += bf16u_to_f_hi(c.z);
        acc[6] += bf16u_to_f_lo(c.w); acc[7] += bf16u_to_f_hi(c.w);
        acc[0] += bf16u_to_f_lo(d.x); acc[1] += bf16u_to_f_hi(d.x);
        acc[2] += bf16u_to_f_lo(d.y); acc[3] += bf16u_to_f_hi(d.y);
        acc[4] += bf16u_to_f_lo(d.z); acc[5] += bf16u_to_f_hi(d.z);
        acc[6] += bf16u_to_f_lo(d.w); acc[7] += bf16u_to_f_hi(d.w);
    }
    for (; j < end; ++j) {
        int d0 = dst_sorted[j];
        uint4 a = *(const uint4*)(xb + (size_t)d0 * 512 + 256 + lane * 16);
        acc[0] += bf16u_to_f_lo(a.x); acc[1] += bf16u_to_f_hi(a.x);
        acc[2] += bf16u_to_f_lo(a.y); acc[3] += bf16u_to_f_hi(a.y);
        acc[4] += bf16u_to_f_lo(a.z); acc[5] += bf16u_to_f_hi(a.z);
        acc[6] += bf16u_to_f_lo(a.w); acc[7] += bf16u_to_f_hi(a.w);
    }
    int deg = end - start;
    float scale = (deg > 0) ? (1.0f / (float)deg) : 1.0f;
    unsigned short r[8];
#pragma unroll
    for (int i = 0; i < 8; ++i) r[i] = f_to_bf16(acc[i] * scale);
    uint4 pk;
    pk.x = pack2(r[0], r[1]);
    pk.y = pack2(r[2], r[3]);
    pk.z = pack2(r[4], r[5]);
    pk.w = pack2(r[6], r[7]);
    *(uint4*)(outb + (size_t)node * 512 + lane * 16) = pk;
}

// ---------------------------------------------------------------------------
// MFMA GEMM: out[m][n] = sum_k A[m][k]*M[n][k], A = bf16 [agg|x] in out rows
// (K=256), M = [W;B]. When bfrag != nullptr the bf16 B-fragments were
// pre-staged in frag-lane order by convert_x_kernel: each block async-copies
// 64 KB straight to LDS via global_load_lds (no VALU convert, no VGPR trip).
// 4 waves/block, each wave 32 rows x 128 cols. In-place safe: each wave reads
// only its own rows before storing them.
// ---------------------------------------------------------------------------
__global__ __launch_bounds__(256) void gemm_mfma_kernel(const float* __restrict__ W,
                                                        const float* __restrict__ Bm,
                                                        const uint4* __restrict__ bfrag,
                                                        float* __restrict__ out, int N) {
    __shared__ uint4 Bs[4096];  // 64 KB: Bs[(nt*8+s)*64 + lane] = 16B B-frag
    int t = threadIdx.x;
    int lane = t & 63;
    int w = t >> 6;
    int m16 = lane & 15;
    int quad = lane >> 4;

    if (bfrag) {
        // ---- async copy pre-staged frags: wave w copies rows [w*16, w*16+16) ----
#pragma unroll
        for (int j = 0; j < 16; ++j)
            gload_lds16(bfrag + (w * 16 + j) * 64 + lane, &Bs[(w * 16 + j) * 64]);
    } else {
        // ---- fallback: convert fp32 W/B -> bf16 frags in-kernel ----
#pragma unroll
        for (int nt2 = 0; nt2 < 2; ++nt2) {
            int nt = w * 2 + nt2;
            int n = nt * 16 + m16;
#pragma unroll
            for (int s = 0; s < 8; ++s) {
                int kbase = s * 32 + quad * 8;
                const float* srcp = (kbase < 128) ? (W + n * 128 + kbase)
                                                  : (Bm + n * 128 + (kbase - 128));
                float4 v0 = *(const float4*)srcp;
                float4 v1 = *(const float4*)(srcp + 4);
                uint4 pk;
                pk.x = pack2(f_to_bf16(v0.x), f_to_bf16(v0.y));
                pk.y = pack2(f_to_bf16(v0.z), f_to_bf16(v0.w));
                pk.z = pack2(f_to_bf16(v1.x), f_to_bf16(v1.y));
                pk.w = pack2(f_to_bf16(v1.z), f_to_bf16(v1.w));
                Bs[(nt * 8 + s) * 64 + lane] = pk;
            }
        }
    }
    __syncthreads();

    // ---- A fragments: 2 row-groups of 16, register-resident ----
    int rowbase = blockIdx.x * 128 + w * 32;
    short8 afrag[2][8];
#pragma unroll
    for (int g = 0; g < 2; ++g) {
        int arow = rowbase + g * 16 + m16;
        if (arow > N - 1) arow = N - 1;  // clamp; NaN only pollutes discarded rows
        const char* ab = (const char*)out + (size_t)arow * 512;
#pragma unroll
        for (int s = 0; s < 8; ++s)
            afrag[g][s] = *(const short8*)(ab + s * 64 + quad * 16);
    }

    floatx4 acc[2][8];
#pragma unroll
    for (int g = 0; g < 2; ++g)
#pragma unroll
        for (int nt = 0; nt < 8; ++nt) acc[g][nt] = (floatx4){0.f, 0.f, 0.f, 0.f};

#pragma unroll
    for (int nt = 0; nt < 8; ++nt) {
#pragma unroll
        for (int s = 0; s < 8; ++s) {
            short8 bf = *(const short8*)&Bs[(nt * 8 + s) * 64 + lane];
            acc[0][nt] = __builtin_amdgcn_mfma_f32_16x16x32_bf16(afrag[0][s], bf, acc[0][nt], 0, 0, 0);
            acc[1][nt] = __builtin_amdgcn_mfma_f32_16x16x32_bf16(afrag[1][s], bf, acc[1][nt], 0, 0, 0);
        }
    }

#pragma unroll
    for (int g = 0; g < 2; ++g)
#pragma unroll
        for (int nt = 0; nt < 8; ++nt)
#pragma unroll
            for (int r = 0; r < 4; ++r) {
                int gr = rowbase + g * 16 + quad * 4 + r;
                if (gr < N) out[(size_t)gr * 128 + nt * 16 + m16] = acc[g][nt][r];
            }
}

// ---------------------------------------------------------------------------
// Atomic-scatter fallback (tiny ws).
// ---------------------------------------------------------------------------
__global__ void invdeg_kernel(int* __restrict__ deg_io, int N) {
    int i = blockIdx.x * blockDim.x + threadIdx.x;
    if (i < N) {
        int d = deg_io[i];
        float inv = (d > 0) ? (1.0f / (float)d) : 1.0f;
        ((float*)deg_io)[i] = inv;
    }
}

__global__ __launch_bounds__(128) void scatter_atomic_kernel(const float* __restrict__ x,
                                                             const int* __restrict__ ei,
                                                             const float* __restrict__ invdeg,
                                                             float* __restrict__ out, int E) {
    int e = blockIdx.x;
    int f = threadIdx.x;
    int s = ei[e];
    int d = ei[E + e];
    float v = x[(long)d * F_IN + f] * invdeg[s];
    atomicAdd(&out[(long)s * F_IN + f], v);
}

__global__ __launch_bounds__(256) void gemm_fused_kernel(const float* __restrict__ x,
                                                         const float* __restrict__ W,
                                                         const float* __restrict__ Bm,
                                                         float* __restrict__ out, int N) {
    __shared__ float As[64][68];
    __shared__ float Ms[64][132];
    int t = threadIdx.x;
    int row0 = blockIdx.x * 64;
    int c0 = (t & 31) * 4;
    int r0 = (t >> 5) * 8;
    float acc[8][4];
#pragma unroll
    for (int i = 0; i < 8; ++i)
#pragma unroll
        for (int j = 0; j < 4; ++j) acc[i][j] = 0.0f;

    for (int kc = 0; kc < 4; ++kc) {
        const float* Asrc = (kc < 2) ? out : x;
        const float* Msrc = (kc < 2) ? W : Bm;
        int k0 = (kc & 1) * 64;
#pragma unroll
        for (int i = 0; i < 4; ++i) {
            int flat = t + 256 * i;
            int m = flat >> 4, ks = flat & 15;
            int row = row0 + m;
            float4 v = make_float4(0.f, 0.f, 0.f, 0.f);
            if (row < N) v = *(const float4*)&Asrc[(long)row * 128 + k0 + ks * 4];
            As[ks * 4 + 0][m] = v.x;
            As[ks * 4 + 1][m] = v.y;
            As[ks * 4 + 2][m] = v.z;
            As[ks * 4 + 3][m] = v.w;
        }
#pragma unroll
        for (int i = 0; i < 8; ++i) {
            int flat = t + 256 * i;
            int c = flat >> 4, ks = flat & 15;
            float4 v = *(const float4*)&Msrc[(long)c * 128 + k0 + ks * 4];
            Ms[ks * 4 + 0][c] = v.x;
            Ms[ks * 4 + 1][c] = v.y;
            Ms[ks * 4 + 2][c] = v.z;
            Ms[ks * 4 + 3][c] = v.w;
        }
        __syncthreads();
#pragma unroll 8
        for (int kk = 0; kk < 64; ++kk) {
            float4 a0 = *(const float4*)&As[kk][r0];
            float4 a1 = *(const float4*)&As[kk][r0 + 4];
            float4 m0 = *(const float4*)&Ms[kk][c0];
            float a[8] = {a0.x, a0.y, a0.z, a0.w, a1.x, a1.y, a1.z, a1.w};
            float m[4] = {m0.x, m0.y, m0.z, m0.w};
#pragma unroll
            for (int i = 0; i < 8; ++i)
#pragma unroll
                for (int j = 0; j < 4; ++j) acc[i][j] += a[i] * m[j];
        }
        __syncthreads();
    }
#pragma unroll
    for (int i = 0; i < 8; ++i) {
        int row = row0 + r0 + i;
        if (row < N) {
            float4 v = make_float4(acc[i][0], acc[i][1], acc[i][2], acc[i][3]);
            *(float4*)&out[(long)row * 128 + c0] = v;
        }
    }
}

// ---------------------------------------------------------------------------

extern "C" void kernel_launch(void* const* d_in, const int* in_sizes, int n_in,
                              void* d_out, int out_size, void* d_ws, size_t ws_size,
                              hipStream_t stream) {
    const float* x = (const float*)d_in[0];
    const int* ei = (const int*)d_in[1];     // int32 per harness contract
    const float* W = (const float*)d_in[2];
    const float* Bm = (const float*)d_in[3];
    float* out = (float*)d_out;

    const int N = in_sizes[0] / F_IN;   // 100000
    const int E = in_sizes[1] / 2;      // 625000
    const int NCHUNK = (N + 1023) / 1024;

    const size_t need_csr    = ((size_t)N + 128 + (size_t)E) * sizeof(int);
    const size_t need_staged = need_csr + 4096 * sizeof(uint4);   // +64KB bfrag
    const size_t need_deg    = (size_t)N * sizeof(int);

    if (ws_size >= need_csr) {
        // -------- primary path: CSR + bf16 gather + LDS-staged MFMA GEMM ----
        bool staged = (ws_size >= need_staged);
        uint4* bfrag;
        int* off;
        if (staged) {
            bfrag = (uint4*)d_ws;            // 64KB, 16B-aligned at ws base
            off   = (int*)(bfrag + 4096);
        } else {
            bfrag = nullptr;
            off   = (int*)d_ws;
        }
        int* partials   = off + N;
        int* dst_sorted = partials + 128;

        zero_kernel<<<256, 256, 0, stream>>>(off, N);
        hist_kernel<<<(E + 255) / 256, 256, 0, stream>>>(ei, off, E);
        chunk_sums_kernel<<<NCHUNK, 256, 0, stream>>>(off, partials, N);
        scan_chunks_kernel<<<NCHUNK, 256, 0, stream>>>(off, partials, N, NCHUNK);
        fill_kernel<<<(E + 255) / 256, 256, 0, stream>>>(ei, off, dst_sorted, E);
        {
            long tot = (long)N * 32;
            int nb = (int)((tot + 255) / 256) + (staged ? 1 : 0);
            convert_x_kernel<<<nb, 256, 0, stream>>>(x, (char*)out, W, Bm, bfrag, N);
        }
        gather_bf16_kernel<<<(N + 15) / 16, 256, 0, stream>>>(off, dst_sorted, (char*)out, N);
        gemm_mfma_kernel<<<(N + 127) / 128, 256, 0, stream>>>(W, Bm, bfrag, out, N);
    } else if (ws_size >= need_deg) {
        // -------- atomic scatter fallback --------
        int* deg = (int*)d_ws;
        zero_kernel<<<256, 256, 0, stream>>>(deg, N);
        hist_kernel<<<(E + 255) / 256, 256, 0, stream>>>(ei, deg, E);
        invdeg_kernel<<<(N + 255) / 256, 256, 0, stream>>>(deg, N);
        zero_kernel<<<512, 256, 0, stream>>>((int*)out, (long)N * F_IN);
        scatter_atomic_kernel<<<E, 128, 0, stream>>>(x, ei, (const float*)deg, out, E);
        gemm_fused_kernel<<<(N + 63) / 64, 256, 0, stream>>>(x, W, Bm, out, N);
    }
}